// Round 7
// baseline (952.769 us; speedup 1.0000x reference)
//
#include <hip/hip_runtime.h>
#include <hip/hip_cooperative_groups.h>

// StandGCN2: 2-layer GCN, N=100000, E=600000, 128->128(relu)->64, bf16 I/O.
// R7: ONE cooperative mega-kernel (6 grid.sync phases) to kill ~13us/dispatch
// launch gaps (R6: ~130us of gaps across 10 dispatches). Phases: zero+probe ->
// cvtw+count -> scan1 -> prefix+ninfo -> fill -> fusedA(tiles) -> agg2.
// Fallback to R6 multi-kernel path if cooperative launch is unavailable.

namespace cg = cooperative_groups;

typedef unsigned short u16;
typedef unsigned int u32;
typedef __attribute__((ext_vector_type(8))) short bf16x8;
typedef __attribute__((ext_vector_type(4))) float f32x4;

__device__ __forceinline__ float b2f(u16 s) {
  return __uint_as_float(((u32)s) << 16);
}
__device__ __forceinline__ u16 f2b(float f) {
  u32 u = __float_as_uint(f);
  u32 r = (u + 0x7FFFu + ((u >> 16) & 1u)) >> 16;
  return (u16)r;
}
__device__ __forceinline__ u32 pk2(float a, float b) {
  return (u32)f2b(a) | ((u32)f2b(b) << 16);
}
__device__ __forceinline__ void dec8(uint4 v, float f[8]) {
  f[0] = __uint_as_float(v.x << 16);
  f[1] = __uint_as_float(v.x & 0xFFFF0000u);
  f[2] = __uint_as_float(v.y << 16);
  f[3] = __uint_as_float(v.y & 0xFFFF0000u);
  f[4] = __uint_as_float(v.z << 16);
  f[5] = __uint_as_float(v.z & 0xFFFF0000u);
  f[6] = __uint_as_float(v.w << 16);
  f[7] = __uint_as_float(v.w & 0xFFFF0000u);
}
__device__ __forceinline__ void fma8(uint4 v, float d, float acc[8]) {
  acc[0] = fmaf(__uint_as_float(v.x << 16), d, acc[0]);
  acc[1] = fmaf(__uint_as_float(v.x & 0xFFFF0000u), d, acc[1]);
  acc[2] = fmaf(__uint_as_float(v.y << 16), d, acc[2]);
  acc[3] = fmaf(__uint_as_float(v.y & 0xFFFF0000u), d, acc[3]);
  acc[4] = fmaf(__uint_as_float(v.z << 16), d, acc[4]);
  acc[5] = fmaf(__uint_as_float(v.z & 0xFFFF0000u), d, acc[5]);
  acc[6] = fmaf(__uint_as_float(v.w << 16), d, acc[6]);
  acc[7] = fmaf(__uint_as_float(v.w & 0xFFFF0000u), d, acc[7]);
}
__device__ __forceinline__ void load8x(const void* xraw, int row, int l16, int mcv,
                                       float f[8]) {
  if (mcv) {
    const float* xp = (const float*)xraw + (size_t)row * 128 + l16 * 8;
    float4 a = *(const float4*)xp;
    float4 b = *(const float4*)(xp + 4);
    f[0] = a.x; f[1] = a.y; f[2] = a.z; f[3] = a.w;
    f[4] = b.x; f[5] = b.y; f[6] = b.z; f[7] = b.w;
  } else {
    uint4 v = *(const uint4*)((const u16*)xraw + (size_t)row * 128 + l16 * 8);
    dec8(v, f);
  }
}

// ================= mega cooperative kernel =================

__global__ __launch_bounds__(256) void mega(
    const void* __restrict__ xraw, const int* __restrict__ ei,
    const void* __restrict__ W1r, const void* __restrict__ b1r,
    const void* __restrict__ W2r, const void* __restrict__ b2r,
    void* __restrict__ outv, int N, int E, int NP, int nw1,
    int* __restrict__ mode, int* __restrict__ cnt, float* __restrict__ dinv,
    int* __restrict__ offs, int* __restrict__ bsum, int* __restrict__ cursor,
    int4* __restrict__ ninfo, int2* __restrict__ sp,
    u16* __restrict__ W1t, u16* __restrict__ b1b,
    u16* __restrict__ W2t, u16* __restrict__ b2b, u16* __restrict__ g) {
  cg::grid_group grid = cg::this_grid();
  __shared__ int lds[256];
  __shared__ __align__(16) u16 As[16 * 136];
  __shared__ __align__(16) u16 Hs[16 * 136];

  const int tid = threadIdx.x;
  const int gsize = gridDim.x;
  const int gtid = blockIdx.x * 256 + tid;
  const int gstride = gsize * 256;
  const int NB = NP >> 8;
  const int* srcA = ei;
  const int* dstA = ei + E;

  // ---- P0: zero cnt; probe dtype (block 0) ----
  for (int i = gtid; i < NP; i += gstride) cnt[i] = 0;
  if (blockIdx.x == 0) {
    if (tid == 0) lds[0] = 0;
    __syncthreads();
    int c = 0;
    for (int j = tid; j < nw1; j += 256) {
      u32 e = (((const u16*)W1r)[j] >> 7) & 0xFFu;
      if (e >= 100u && e <= 130u) c++;
    }
    atomicAdd(&lds[0], c);
    __syncthreads();
    if (tid == 0) *mode = (lds[0] < (nw1 / 16) * 13) ? 1 : 0;  // 1 = fp32
  }
  grid.sync();

  // ---- P1: convert weights (transposed) + degree count ----
  {
    int m = *mode;
    for (int i = gtid; i < 24768; i += gstride) {
      int j = i;
      const void* src;
      u16* dst;
      int sidx, didx;
      if (j < 16384) {
        int nn = j >> 7, k = j & 127;
        src = W1r; dst = W1t; sidx = k * 128 + nn; didx = j;
      } else if ((j -= 16384) < 128) {
        src = b1r; dst = b1b; sidx = j; didx = j;
      } else if ((j -= 128) < 8192) {
        int nn = j >> 7, k = j & 127;
        src = W2r; dst = W2t; sidx = k * 64 + nn; didx = j;
      } else {
        j -= 8192;
        src = b2r; dst = b2b; sidx = j; didx = j;
      }
      dst[didx] = m ? f2b(((const float*)src)[sidx]) : ((const u16*)src)[sidx];
    }
    for (int e = gtid; e < E; e += gstride) atomicAdd(&cnt[dstA[e]], 1);
  }
  grid.sync();

  // ---- P2: per-chunk (256) exclusive scan, chunk totals -> bsum ----
  for (int b = blockIdx.x; b < NB; b += gsize) {
    int i = b * 256 + tid;
    int v = cnt[i];
    lds[tid] = v;
    __syncthreads();
#pragma unroll
    for (int off = 1; off < 256; off <<= 1) {
      int add = (tid >= off) ? lds[tid - off] : 0;
      __syncthreads();
      lds[tid] += add;
      __syncthreads();
    }
    offs[i] = lds[tid] - v;
    if (tid == 0) bsum[b] = lds[255];
    __syncthreads();
  }
  grid.sync();

  // ---- P3: chunk-prefix (parallel sum of bsum[0..b)) + cursor/dinv/ninfo ----
  for (int b = blockIdx.x; b < NB; b += gsize) {
    int part = 0;
    for (int t = tid; t < b; t += 256) part += bsum[t];
    lds[tid] = part;
    __syncthreads();
#pragma unroll
    for (int off = 128; off > 0; off >>= 1) {
      if (tid < off) lds[tid] += lds[tid + off];
      __syncthreads();
    }
    int pre = lds[0];
    __syncthreads();
    int i = b * 256 + tid;
    int o = offs[i] + pre;
    cursor[i] = o;
    int c = cnt[i];
    float dv = rsqrtf((float)c + 1.0f);  // +1 self-loop
    dinv[i] = dv;
    ninfo[i] = make_int4(o, c, __float_as_int(dv), 0);
    __syncthreads();
  }
  grid.sync();

  // ---- P4: fill per-edge {src, dinv[src]} ----
  for (int e = gtid; e < E; e += gstride) {
    int s = srcA[e];
    float ds = dinv[s];
    int p = atomicAdd(&cursor[dstA[e]], 1);
    sp[p] = make_int2(s, __float_as_int(ds));
  }
  grid.sync();

  // ---- P5: fusedA — gather Ax (16 nodes/block) + MFMA W1(relu,b1) + MFMA W2 -> g ----
  {
    const int wv = tid >> 6, lane = tid & 63;
    const int lq = lane >> 4, lr = lane & 15;
    const int mcv = *mode;
    const int tiles = (N + 15) >> 4;
    for (int t = blockIdx.x; t < tiles; t += gsize) {
      const int base = t * 16;
      const int i = base + wv * 4 + lq;
      const bool valid = (i < N);

      int start = 0, c = 0;
      float di = 0.f;
      if (valid) {
        int4 ni = ninfo[i];
        start = ni.x;
        c = ni.y;
        di = __int_as_float(ni.z);
      }
      float acc[8];
      {
        float f[8] = {0.f, 0.f, 0.f, 0.f, 0.f, 0.f, 0.f, 0.f};
        if (valid) load8x(xraw, i, lr, mcv, f);
#pragma unroll
        for (int j = 0; j < 8; ++j) acc[j] = f[j] * di;
      }
      const int bl = lq * 16;
      for (int bs = 0; __any(bs < c); bs += 16) {
        int m = c - bs;
        m = m < 0 ? 0 : (m > 16 ? 16 : m);
        int s = 0, db = 0;
        if (lr < m) {
          int2 p = sp[start + bs + lr];
          s = p.x;
          db = p.y;
        }
        int mmw = m;
        mmw = max(mmw, __shfl_xor(mmw, 16));
        mmw = max(mmw, __shfl_xor(mmw, 32));
        for (int e = 0; e < mmw; e += 4) {
          int s0 = __shfl(s, bl + e), s1 = __shfl(s, bl + e + 1);
          int s2 = __shfl(s, bl + e + 2), s3 = __shfl(s, bl + e + 3);
          float d0 = __int_as_float(__shfl(db, bl + e));
          float d1 = __int_as_float(__shfl(db, bl + e + 1));
          float d2 = __int_as_float(__shfl(db, bl + e + 2));
          float d3 = __int_as_float(__shfl(db, bl + e + 3));
          float f0[8], f1[8], f2[8], f3[8];
          load8x(xraw, s0, lr, mcv, f0);
          load8x(xraw, s1, lr, mcv, f1);
          load8x(xraw, s2, lr, mcv, f2);
          load8x(xraw, s3, lr, mcv, f3);
#pragma unroll
          for (int j = 0; j < 8; ++j)
            acc[j] = fmaf(f0[j], d0,
                     fmaf(f1[j], d1, fmaf(f2[j], d2, fmaf(f3[j], d3, acc[j]))));
        }
      }
      {
        uint4 ov;
        ov.x = pk2(acc[0] * di, acc[1] * di);
        ov.y = pk2(acc[2] * di, acc[3] * di);
        ov.z = pk2(acc[4] * di, acc[5] * di);
        ov.w = pk2(acc[6] * di, acc[7] * di);
        *(uint4*)&As[(wv * 4 + lq) * 136 + lr * 8] = ov;
      }
      __syncthreads();

      // W1: wave wv -> col tiles 2wv, 2wv+1
      bf16x8 a[4];
#pragma unroll
      for (int s = 0; s < 4; ++s)
        a[s] = *(const bf16x8*)&As[lr * 136 + s * 32 + lq * 8];
#pragma unroll
      for (int tt = 0; tt < 2; ++tt) {
        const int nt = wv * 2 + tt;
        f32x4 acc4 = {0.f, 0.f, 0.f, 0.f};
#pragma unroll
        for (int s = 0; s < 4; ++s) {
          bf16x8 b = *(const bf16x8*)&W1t[(nt * 16 + lr) * 128 + s * 32 + lq * 8];
          acc4 = __builtin_amdgcn_mfma_f32_16x16x32_bf16(a[s], b, acc4, 0, 0, 0);
        }
        float bb = b2f(b1b[nt * 16 + lr]);
#pragma unroll
        for (int r = 0; r < 4; ++r) {
          float o = fmaxf(acc4[r] + bb, 0.f);
          Hs[(lq * 4 + r) * 136 + nt * 16 + lr] = f2b(o);
        }
      }
      __syncthreads();

      // W2: wave wv -> col tile wv
      bf16x8 a2[4];
#pragma unroll
      for (int s = 0; s < 4; ++s)
        a2[s] = *(const bf16x8*)&Hs[lr * 136 + s * 32 + lq * 8];
      {
        const int nt = wv;
        f32x4 acc4 = {0.f, 0.f, 0.f, 0.f};
#pragma unroll
        for (int s = 0; s < 4; ++s) {
          bf16x8 b = *(const bf16x8*)&W2t[(nt * 16 + lr) * 128 + s * 32 + lq * 8];
          acc4 = __builtin_amdgcn_mfma_f32_16x16x32_bf16(a2[s], b, acc4, 0, 0, 0);
        }
#pragma unroll
        for (int r = 0; r < 4; ++r) {
          int row = base + lq * 4 + r;
          if (row < N) g[(size_t)row * 64 + nt * 16 + lr] = f2b(acc4[r]);
        }
      }
    }
  }
  grid.sync();

  // ---- P6: agg2 — oct-wave gather over g (+b2) -> out ----
  {
    const int lane = tid & 63;
    const int o8 = lane >> 3, l8 = lane & 7;
    const int mcv = *mode;
    const int groups = (N + 31) >> 5;
    for (int t = blockIdx.x; t < groups; t += gsize) {
      const int i = t * 32 + (tid >> 6) * 8 + o8;
      const bool valid = (i < N);
      int start = 0, c = 0;
      float di = 0.f;
      if (valid) {
        int4 ni = ninfo[i];
        start = ni.x;
        c = ni.y;
        di = __int_as_float(ni.z);
      }
      float acc[8];
      {
        uint4 v = valid ? *(const uint4*)(g + (size_t)i * 64 + l8 * 8)
                        : make_uint4(0u, 0u, 0u, 0u);
        float f[8];
        dec8(v, f);
#pragma unroll
        for (int j = 0; j < 8; ++j) acc[j] = f[j] * di;
      }
      const int bl = o8 * 8;
      for (int base = 0; __any(base < c); base += 8) {
        int m = c - base;
        m = m < 0 ? 0 : (m > 8 ? 8 : m);
        int s = 0, db = 0;
        if (l8 < m) {
          int2 p = sp[start + base + l8];
          s = p.x;
          db = p.y;
        }
        int mmw = m;
        mmw = max(mmw, __shfl_xor(mmw, 8));
        mmw = max(mmw, __shfl_xor(mmw, 16));
        mmw = max(mmw, __shfl_xor(mmw, 32));
        for (int e = 0; e < mmw; e += 4) {
          int s0 = __shfl(s, bl + e), s1 = __shfl(s, bl + e + 1);
          int s2 = __shfl(s, bl + e + 2), s3 = __shfl(s, bl + e + 3);
          float d0 = __int_as_float(__shfl(db, bl + e));
          float d1 = __int_as_float(__shfl(db, bl + e + 1));
          float d2 = __int_as_float(__shfl(db, bl + e + 2));
          float d3 = __int_as_float(__shfl(db, bl + e + 3));
          uint4 v0 = *(const uint4*)(g + (size_t)s0 * 64 + l8 * 8);
          uint4 v1 = *(const uint4*)(g + (size_t)s1 * 64 + l8 * 8);
          uint4 v2 = *(const uint4*)(g + (size_t)s2 * 64 + l8 * 8);
          uint4 v3 = *(const uint4*)(g + (size_t)s3 * 64 + l8 * 8);
          fma8(v0, d0, acc);
          fma8(v1, d1, acc);
          fma8(v2, d2, acc);
          fma8(v3, d3, acc);
        }
      }
      if (valid) {
        uint4 bv = *(const uint4*)(b2b + l8 * 8);
        float bf[8];
        dec8(bv, bf);
        float o[8];
#pragma unroll
        for (int j = 0; j < 8; ++j) o[j] = fmaf(acc[j], di, bf[j]);
        if (mcv) {
          float* op = (float*)outv + (size_t)i * 64 + l8 * 8;
          *(float4*)op = make_float4(o[0], o[1], o[2], o[3]);
          *(float4*)(op + 4) = make_float4(o[4], o[5], o[6], o[7]);
        } else {
          uint4 ov;
          ov.x = pk2(o[0], o[1]);
          ov.y = pk2(o[2], o[3]);
          ov.z = pk2(o[4], o[5]);
          ov.w = pk2(o[6], o[7]);
          *(uint4*)((u16*)outv + (size_t)i * 64 + l8 * 8) = ov;
        }
      }
    }
  }
}

// ================= fallback multi-kernel path (R6) =================

__global__ __launch_bounds__(256) void zero_probe_k(const u16* __restrict__ w,
                                                    int* __restrict__ mode,
                                                    int* __restrict__ cnt, int np,
                                                    int nu16) {
  int i = blockIdx.x * 256 + threadIdx.x;
  if (i < np) cnt[i] = 0;
  if (blockIdx.x == 0) {
    __shared__ int cnt_s;
    if (threadIdx.x == 0) cnt_s = 0;
    __syncthreads();
    int c = 0;
    for (int j = threadIdx.x; j < nu16; j += 256) {
      u32 e = (w[j] >> 7) & 0xFFu;
      if (e >= 100u && e <= 130u) c++;
    }
    atomicAdd(&cnt_s, c);
    __syncthreads();
    if (threadIdx.x == 0) *mode = (cnt_s < (nu16 / 16) * 13) ? 1 : 0;
  }
}

__global__ __launch_bounds__(256) void cvtw_k(const void* W1, const void* b1,
                                              const void* W2, const void* b2,
                                              u16* __restrict__ W1t, u16* __restrict__ ob1,
                                              u16* __restrict__ W2t, u16* __restrict__ ob2,
                                              const int* __restrict__ mode) {
  int m = *mode;
  int i = blockIdx.x * 256 + threadIdx.x;
  int j = i;
  const void* src;
  u16* dst;
  int sidx, didx;
  if (j < 16384) {
    int n = j >> 7, k = j & 127;
    src = W1; dst = W1t; sidx = k * 128 + n; didx = j;
  } else if ((j -= 16384) < 128) {
    src = b1; dst = ob1; sidx = j; didx = j;
  } else if ((j -= 128) < 8192) {
    int n = j >> 7, k = j & 127;
    src = W2; dst = W2t; sidx = k * 64 + n; didx = j;
  } else if ((j -= 8192) < 64) {
    src = b2; dst = ob2; sidx = j; didx = j;
  } else
    return;
  dst[didx] = m ? f2b(((const float*)src)[sidx]) : ((const u16*)src)[sidx];
}

__global__ __launch_bounds__(256) void count_k(const int* __restrict__ dst,
                                               int* __restrict__ cnt, int E) {
  int e = blockIdx.x * 256 + threadIdx.x;
  if (e < E) atomicAdd(&cnt[dst[e]], 1);
}

__global__ __launch_bounds__(256) void scan1(const int* __restrict__ cnt,
                                             int* __restrict__ offs,
                                             int* __restrict__ bsum, int np) {
  __shared__ int lds[256];
  int t = threadIdx.x;
  int i = blockIdx.x * 256 + t;
  int v = cnt[i];
  lds[t] = v;
  __syncthreads();
#pragma unroll
  for (int off = 1; off < 256; off <<= 1) {
    int add = (t >= off) ? lds[t - off] : 0;
    __syncthreads();
    lds[t] += add;
    __syncthreads();
  }
  offs[i] = lds[t] - v;
  if (t == 0) bsum[blockIdx.x] = lds[255];
}

__global__ __launch_bounds__(512) void scan2(const int* __restrict__ bsum,
                                             int* __restrict__ bscan, int nb) {
  __shared__ int lds[512];
  int t = threadIdx.x;
  int v = (t < nb) ? bsum[t] : 0;
  lds[t] = v;
  __syncthreads();
#pragma unroll
  for (int off = 1; off < 512; off <<= 1) {
    int add = (t >= off) ? lds[t - off] : 0;
    __syncthreads();
    lds[t] += add;
    __syncthreads();
  }
  bscan[t] = lds[t] - v;
}

__global__ __launch_bounds__(256) void scan3(const int* __restrict__ offs,
                                             const int* __restrict__ bscan,
                                             int* __restrict__ cursor,
                                             const int* __restrict__ cnt,
                                             float* __restrict__ dinv,
                                             int4* __restrict__ ninfo, int np) {
  int i = blockIdx.x * 256 + threadIdx.x;
  int o = offs[i] + bscan[blockIdx.x];
  cursor[i] = o;
  int c = cnt[i];
  float dv = rsqrtf((float)c + 1.0f);
  dinv[i] = dv;
  ninfo[i] = make_int4(o, c, __float_as_int(dv), 0);
}

__global__ __launch_bounds__(256) void fill_k(const int* __restrict__ src,
                                              const int* __restrict__ dst,
                                              int* __restrict__ cursor,
                                              const float* __restrict__ dinv,
                                              int2* __restrict__ sp, int E) {
  int e = blockIdx.x * 256 + threadIdx.x;
  if (e < E) {
    int s = src[e];
    float ds = dinv[s];
    int p = atomicAdd(&cursor[dst[e]], 1);
    sp[p] = make_int2(s, __float_as_int(ds));
  }
}

__global__ __launch_bounds__(256) void fusedA_k(const void* __restrict__ xraw,
                                                const int2* __restrict__ sp,
                                                const int4* __restrict__ ninfo,
                                                const u16* __restrict__ W1t,
                                                const u16* __restrict__ b1,
                                                const u16* __restrict__ W2t,
                                                u16* __restrict__ g, int n,
                                                const int* __restrict__ mode) {
  __shared__ __align__(16) u16 As[16 * 136];
  __shared__ __align__(16) u16 Hs[16 * 136];
  const int tid = threadIdx.x, wv = tid >> 6, lane = tid & 63;
  const int lq = lane >> 4, lr = lane & 15;
  const int mcv = *mode;
  const int base = blockIdx.x * 16;
  const int i = base + wv * 4 + lq;
  const bool valid = (i < n);

  int start = 0, c = 0;
  float di = 0.f;
  if (valid) {
    int4 ni = ninfo[i];
    start = ni.x;
    c = ni.y;
    di = __int_as_float(ni.z);
  }
  float acc[8];
  {
    float f[8] = {0.f, 0.f, 0.f, 0.f, 0.f, 0.f, 0.f, 0.f};
    if (valid) load8x(xraw, i, lr, mcv, f);
#pragma unroll
    for (int j = 0; j < 8; ++j) acc[j] = f[j] * di;
  }
  const int bl = lq * 16;
  for (int bs = 0; __any(bs < c); bs += 16) {
    int m = c - bs;
    m = m < 0 ? 0 : (m > 16 ? 16 : m);
    int s = 0, db = 0;
    if (lr < m) {
      int2 p = sp[start + bs + lr];
      s = p.x;
      db = p.y;
    }
    int mmw = m;
    mmw = max(mmw, __shfl_xor(mmw, 16));
    mmw = max(mmw, __shfl_xor(mmw, 32));
    for (int e = 0; e < mmw; e += 4) {
      int s0 = __shfl(s, bl + e), s1 = __shfl(s, bl + e + 1);
      int s2 = __shfl(s, bl + e + 2), s3 = __shfl(s, bl + e + 3);
      float d0 = __int_as_float(__shfl(db, bl + e));
      float d1 = __int_as_float(__shfl(db, bl + e + 1));
      float d2 = __int_as_float(__shfl(db, bl + e + 2));
      float d3 = __int_as_float(__shfl(db, bl + e + 3));
      float f0[8], f1[8], f2[8], f3[8];
      load8x(xraw, s0, lr, mcv, f0);
      load8x(xraw, s1, lr, mcv, f1);
      load8x(xraw, s2, lr, mcv, f2);
      load8x(xraw, s3, lr, mcv, f3);
#pragma unroll
      for (int j = 0; j < 8; ++j)
        acc[j] = fmaf(f0[j], d0,
                 fmaf(f1[j], d1, fmaf(f2[j], d2, fmaf(f3[j], d3, acc[j]))));
    }
  }
  {
    uint4 ov;
    ov.x = pk2(acc[0] * di, acc[1] * di);
    ov.y = pk2(acc[2] * di, acc[3] * di);
    ov.z = pk2(acc[4] * di, acc[5] * di);
    ov.w = pk2(acc[6] * di, acc[7] * di);
    *(uint4*)&As[(wv * 4 + lq) * 136 + lr * 8] = ov;
  }
  __syncthreads();

  bf16x8 a[4];
#pragma unroll
  for (int s = 0; s < 4; ++s)
    a[s] = *(const bf16x8*)&As[lr * 136 + s * 32 + lq * 8];
#pragma unroll
  for (int t = 0; t < 2; ++t) {
    const int nt = wv * 2 + t;
    f32x4 acc4 = {0.f, 0.f, 0.f, 0.f};
#pragma unroll
    for (int s = 0; s < 4; ++s) {
      bf16x8 b = *(const bf16x8*)&W1t[(nt * 16 + lr) * 128 + s * 32 + lq * 8];
      acc4 = __builtin_amdgcn_mfma_f32_16x16x32_bf16(a[s], b, acc4, 0, 0, 0);
    }
    float bb = b2f(b1[nt * 16 + lr]);
#pragma unroll
    for (int r = 0; r < 4; ++r) {
      float o = fmaxf(acc4[r] + bb, 0.f);
      Hs[(lq * 4 + r) * 136 + nt * 16 + lr] = f2b(o);
    }
  }
  __syncthreads();

  bf16x8 a2[4];
#pragma unroll
  for (int s = 0; s < 4; ++s)
    a2[s] = *(const bf16x8*)&Hs[lr * 136 + s * 32 + lq * 8];
  {
    const int nt = wv;
    f32x4 acc4 = {0.f, 0.f, 0.f, 0.f};
#pragma unroll
    for (int s = 0; s < 4; ++s) {
      bf16x8 b = *(const bf16x8*)&W2t[(nt * 16 + lr) * 128 + s * 32 + lq * 8];
      acc4 = __builtin_amdgcn_mfma_f32_16x16x32_bf16(a2[s], b, acc4, 0, 0, 0);
    }
#pragma unroll
    for (int r = 0; r < 4; ++r) {
      int row = base + lq * 4 + r;
      if (row < n) g[(size_t)row * 64 + nt * 16 + lr] = f2b(acc4[r]);
    }
  }
}

__global__ __launch_bounds__(256) void agg2_k(const u16* __restrict__ g,
                                              const int2* __restrict__ sp,
                                              const int4* __restrict__ ninfo,
                                              const u16* __restrict__ b2,
                                              void* __restrict__ outv, int n,
                                              const int* __restrict__ mode) {
  const int lane = threadIdx.x & 63;
  const int o8 = lane >> 3, l8 = lane & 7;
  const int i = blockIdx.x * 32 + (threadIdx.x >> 6) * 8 + o8;
  const bool valid = (i < n);

  int start = 0, c = 0;
  float di = 0.f;
  if (valid) {
    int4 ni = ninfo[i];
    start = ni.x;
    c = ni.y;
    di = __int_as_float(ni.z);
  }
  float acc[8];
  {
    uint4 v = valid ? *(const uint4*)(g + (size_t)i * 64 + l8 * 8)
                    : make_uint4(0u, 0u, 0u, 0u);
    float f[8];
    dec8(v, f);
#pragma unroll
    for (int j = 0; j < 8; ++j) acc[j] = f[j] * di;
  }
  const int bl = o8 * 8;
  for (int base = 0; __any(base < c); base += 8) {
    int m = c - base;
    m = m < 0 ? 0 : (m > 8 ? 8 : m);
    int s = 0, db = 0;
    if (l8 < m) {
      int2 p = sp[start + base + l8];
      s = p.x;
      db = p.y;
    }
    int mmw = m;
    mmw = max(mmw, __shfl_xor(mmw, 8));
    mmw = max(mmw, __shfl_xor(mmw, 16));
    mmw = max(mmw, __shfl_xor(mmw, 32));
    for (int e = 0; e < mmw; e += 4) {
      int s0 = __shfl(s, bl + e), s1 = __shfl(s, bl + e + 1);
      int s2 = __shfl(s, bl + e + 2), s3 = __shfl(s, bl + e + 3);
      float d0 = __int_as_float(__shfl(db, bl + e));
      float d1 = __int_as_float(__shfl(db, bl + e + 1));
      float d2 = __int_as_float(__shfl(db, bl + e + 2));
      float d3 = __int_as_float(__shfl(db, bl + e + 3));
      uint4 v0 = *(const uint4*)(g + (size_t)s0 * 64 + l8 * 8);
      uint4 v1 = *(const uint4*)(g + (size_t)s1 * 64 + l8 * 8);
      uint4 v2 = *(const uint4*)(g + (size_t)s2 * 64 + l8 * 8);
      uint4 v3 = *(const uint4*)(g + (size_t)s3 * 64 + l8 * 8);
      fma8(v0, d0, acc);
      fma8(v1, d1, acc);
      fma8(v2, d2, acc);
      fma8(v3, d3, acc);
    }
  }
  if (valid) {
    uint4 bv = *(const uint4*)(b2 + l8 * 8);
    float bf[8];
    dec8(bv, bf);
    float o[8];
#pragma unroll
    for (int j = 0; j < 8; ++j) o[j] = fmaf(acc[j], di, bf[j]);
    if (*mode) {
      float* op = (float*)outv + (size_t)i * 64 + l8 * 8;
      *(float4*)op = make_float4(o[0], o[1], o[2], o[3]);
      *(float4*)(op + 4) = make_float4(o[4], o[5], o[6], o[7]);
    } else {
      uint4 ov;
      ov.x = pk2(o[0], o[1]);
      ov.y = pk2(o[2], o[3]);
      ov.z = pk2(o[4], o[5]);
      ov.w = pk2(o[6], o[7]);
      *(uint4*)((u16*)outv + (size_t)i * 64 + l8 * 8) = ov;
    }
  }
}

// ================= launch =================

extern "C" void kernel_launch(void* const* d_in, const int* in_sizes, int n_in,
                              void* d_out, int out_size, void* d_ws, size_t ws_size,
                              hipStream_t stream) {
  const void* x_raw  = d_in[0];
  const int*  ei     = (const int*)d_in[1];
  const void* W1_raw = d_in[2];
  const void* b1_raw = d_in[3];
  const void* W2_raw = d_in[4];
  const void* b2_raw = d_in[5];

  int N = in_sizes[0] / 128;
  int E = in_sizes[1] / 2;
  int nw1 = in_sizes[2];
  int NP = ((N + 255) / 256) * 256;
  const int NB = NP / 256;

  char* ws = (char*)d_ws;
  size_t off = 0;
  auto alloc = [&](size_t bytes) -> void* {
    void* p = ws + off;
    off = (off + bytes + 255) & ~(size_t)255;
    return p;
  };
  int*   mode   = (int*)alloc(4);
  int*   cnt    = (int*)alloc((size_t)NP * 4);
  float* dinv   = (float*)alloc((size_t)NP * 4);
  int*   offs   = (int*)alloc((size_t)NP * 4);
  int*   cursor = (int*)alloc((size_t)NP * 4);
  int*   bsum   = (int*)alloc(1024 * 4);
  int*   bscan  = (int*)alloc(1024 * 4);
  int4*  ninfo  = (int4*)alloc((size_t)NP * 16);
  int2*  sp     = (int2*)alloc((size_t)E * 8);
  u16*   W1t    = (u16*)alloc((size_t)128 * 128 * 2);
  u16*   b1b    = (u16*)alloc(128 * 2);
  u16*   W2t    = (u16*)alloc((size_t)64 * 128 * 2);
  u16*   b2b    = (u16*)alloc(64 * 2);
  u16*   g      = (u16*)alloc((size_t)N * 64 * 2);

  // ---- try single cooperative mega-kernel ----
  void* outv = d_out;
  void* args[] = {
    (void*)&x_raw, (void*)&ei, (void*)&W1_raw, (void*)&b1_raw,
    (void*)&W2_raw, (void*)&b2_raw, (void*)&outv,
    (void*)&N, (void*)&E, (void*)&NP, (void*)&nw1,
    (void*)&mode, (void*)&cnt, (void*)&dinv, (void*)&offs, (void*)&bsum,
    (void*)&cursor, (void*)&ninfo, (void*)&sp,
    (void*)&W1t, (void*)&b1b, (void*)&W2t, (void*)&b2b, (void*)&g,
  };
  hipError_t le = hipLaunchCooperativeKernel((const void*)mega, dim3(1024),
                                             dim3(256), args, 0, stream);
  if (le == hipSuccess) return;

  // ---- fallback: R6 multi-kernel path ----
  zero_probe_k<<<NB, 256, 0, stream>>>((const u16*)W1_raw, mode, cnt, NP, nw1);
  cvtw_k<<<(24768 + 255) / 256, 256, 0, stream>>>(W1_raw, b1_raw, W2_raw, b2_raw,
                                                  W1t, b1b, W2t, b2b, mode);
  const int eb = (E + 255) / 256;
  count_k<<<eb, 256, 0, stream>>>(ei + E, cnt, E);
  scan1<<<NB, 256, 0, stream>>>(cnt, offs, bsum, NP);
  scan2<<<1, 512, 0, stream>>>(bsum, bscan, NB);
  scan3<<<NB, 256, 0, stream>>>(offs, bscan, cursor, cnt, dinv, ninfo, NP);
  fill_k<<<eb, 256, 0, stream>>>(ei, ei + E, cursor, dinv, sp, E);
  fusedA_k<<<(N + 15) / 16, 256, 0, stream>>>(x_raw, sp, ninfo, W1t, b1b, W2t, g, N, mode);
  agg2_k<<<(N + 31) / 32, 256, 0, stream>>>(g, sp, ninfo, b2b, d_out, N, mode);
}

// Round 8
// 249.139 us; speedup vs baseline: 3.8243x; 3.8243x over previous
//
#include <hip/hip_runtime.h>

// StandGCN2: 2-layer GCN, N=100000, E=600000, 128->128(relu)->64, bf16 I/O.
// R8: back to multi-kernel (R7 coop grid.sync cost ~120us/sync -> 850us, dead end).
// 7 dispatches: prep(zero+probe+cvtw, block-local probe) -> count -> scan1 ->
// scan23(merged) -> fill -> fusedA(gather+MFMA W1,relu,b1+MFMA W2) -> agg2.
// Gathers use unroll-8 clusters (8 uint4 loads in flight per lane).

typedef unsigned short u16;
typedef unsigned int u32;
typedef __attribute__((ext_vector_type(8))) short bf16x8;
typedef __attribute__((ext_vector_type(4))) float f32x4;

__device__ __forceinline__ float b2f(u16 s) {
  return __uint_as_float(((u32)s) << 16);
}
__device__ __forceinline__ u16 f2b(float f) {
  u32 u = __float_as_uint(f);
  u32 r = (u + 0x7FFFu + ((u >> 16) & 1u)) >> 16;
  return (u16)r;
}
__device__ __forceinline__ u32 pk2(float a, float b) {
  return (u32)f2b(a) | ((u32)f2b(b) << 16);
}
__device__ __forceinline__ void dec8(uint4 v, float f[8]) {
  f[0] = __uint_as_float(v.x << 16);
  f[1] = __uint_as_float(v.x & 0xFFFF0000u);
  f[2] = __uint_as_float(v.y << 16);
  f[3] = __uint_as_float(v.y & 0xFFFF0000u);
  f[4] = __uint_as_float(v.z << 16);
  f[5] = __uint_as_float(v.z & 0xFFFF0000u);
  f[6] = __uint_as_float(v.w << 16);
  f[7] = __uint_as_float(v.w & 0xFFFF0000u);
}
__device__ __forceinline__ void fma8(uint4 v, float d, float acc[8]) {
  acc[0] = fmaf(__uint_as_float(v.x << 16), d, acc[0]);
  acc[1] = fmaf(__uint_as_float(v.x & 0xFFFF0000u), d, acc[1]);
  acc[2] = fmaf(__uint_as_float(v.y << 16), d, acc[2]);
  acc[3] = fmaf(__uint_as_float(v.y & 0xFFFF0000u), d, acc[3]);
  acc[4] = fmaf(__uint_as_float(v.z << 16), d, acc[4]);
  acc[5] = fmaf(__uint_as_float(v.z & 0xFFFF0000u), d, acc[5]);
  acc[6] = fmaf(__uint_as_float(v.w << 16), d, acc[6]);
  acc[7] = fmaf(__uint_as_float(v.w & 0xFFFF0000u), d, acc[7]);
}
__device__ __forceinline__ void load8x(const void* xraw, int row, int l16, int mcv,
                                       float f[8]) {
  if (mcv) {
    const float* xp = (const float*)xraw + (size_t)row * 128 + l16 * 8;
    float4 a = *(const float4*)xp;
    float4 b = *(const float4*)(xp + 4);
    f[0] = a.x; f[1] = a.y; f[2] = a.z; f[3] = a.w;
    f[4] = b.x; f[5] = b.y; f[6] = b.z; f[7] = b.w;
  } else {
    uint4 v = *(const uint4*)((const u16*)xraw + (size_t)row * 128 + l16 * 8);
    dec8(v, f);
  }
}

// ---- prep: zero cnt + block-local dtype probe + weight convert (1 dispatch) ----
// Probe: every block reads the SAME 4096 u16s of W1 -> deterministic mode per
// block (bf16 ~100% exponents in [100,130]; fp32-as-u16 ~55%). Threshold 13/16.

__global__ __launch_bounds__(256) void prep_k(const void* __restrict__ W1,
                                              const void* __restrict__ b1,
                                              const void* __restrict__ W2,
                                              const void* __restrict__ b2,
                                              u16* __restrict__ W1t, u16* __restrict__ ob1,
                                              u16* __restrict__ W2t, u16* __restrict__ ob2,
                                              int* __restrict__ mode,
                                              int* __restrict__ cnt, int np) {
  __shared__ int cnt_s;
  const int tid = threadIdx.x;
  int i = blockIdx.x * 256 + tid;
  if (i < np) cnt[i] = 0;

  if (tid == 0) cnt_s = 0;
  __syncthreads();
  int c = 0;
  for (int j = tid; j < 4096; j += 256) {
    u32 e = (((const u16*)W1)[j] >> 7) & 0xFFu;
    if (e >= 100u && e <= 130u) c++;
  }
  atomicAdd(&cnt_s, c);
  __syncthreads();
  const int m = (cnt_s < 3328) ? 1 : 0;  // 1 = fp32
  if (blockIdx.x == 0 && tid == 0) *mode = m;

  if (i < 24768) {
    int j = i;
    const void* src;
    u16* dst;
    int sidx, didx;
    if (j < 16384) {
      int nn = j >> 7, k = j & 127;
      src = W1; dst = W1t; sidx = k * 128 + nn; didx = j;
    } else if ((j -= 16384) < 128) {
      src = b1; dst = ob1; sidx = j; didx = j;
    } else if ((j -= 128) < 8192) {
      int nn = j >> 7, k = j & 127;
      src = W2; dst = W2t; sidx = k * 64 + nn; didx = j;
    } else {
      j -= 8192;
      src = b2; dst = ob2; sidx = j; didx = j;
    }
    dst[didx] = m ? f2b(((const float*)src)[sidx]) : ((const u16*)src)[sidx];
  }
}

// ---------------- CSR build ----------------

__global__ __launch_bounds__(256) void count_k(const int* __restrict__ dst,
                                               int* __restrict__ cnt, int E) {
  int e = blockIdx.x * 256 + threadIdx.x;
  if (e < E) atomicAdd(&cnt[dst[e]], 1);
}

__global__ __launch_bounds__(256) void scan1(const int* __restrict__ cnt,
                                             int* __restrict__ offs,
                                             int* __restrict__ bsum, int np) {
  __shared__ int lds[256];
  int t = threadIdx.x;
  int i = blockIdx.x * 256 + t;
  int v = cnt[i];
  lds[t] = v;
  __syncthreads();
#pragma unroll
  for (int off = 1; off < 256; off <<= 1) {
    int add = (t >= off) ? lds[t - off] : 0;
    __syncthreads();
    lds[t] += add;
    __syncthreads();
  }
  offs[i] = lds[t] - v;
  if (t == 0) bsum[blockIdx.x] = lds[255];
}

// merged scan2+scan3: block b parallel-sums bsum[0..b), then finalizes
__global__ __launch_bounds__(256) void scan23(const int* __restrict__ offs,
                                              const int* __restrict__ bsum,
                                              int* __restrict__ cursor,
                                              const int* __restrict__ cnt,
                                              float* __restrict__ dinv,
                                              int4* __restrict__ ninfo, int np) {
  __shared__ int lds[256];
  const int t = threadIdx.x, b = blockIdx.x;
  int part = 0;
  for (int k = t; k < b; k += 256) part += bsum[k];
  lds[t] = part;
  __syncthreads();
#pragma unroll
  for (int off = 128; off > 0; off >>= 1) {
    if (t < off) lds[t] += lds[t + off];
    __syncthreads();
  }
  const int pre = lds[0];
  int i = b * 256 + t;
  int o = offs[i] + pre;
  cursor[i] = o;
  int c = cnt[i];
  float dv = rsqrtf((float)c + 1.0f);  // +1 self-loop
  dinv[i] = dv;
  ninfo[i] = make_int4(o, c, __float_as_int(dv), 0);
}

__global__ __launch_bounds__(256) void fill_k(const int* __restrict__ src,
                                              const int* __restrict__ dst,
                                              int* __restrict__ cursor,
                                              const float* __restrict__ dinv,
                                              int2* __restrict__ sp, int E) {
  int e = blockIdx.x * 256 + threadIdx.x;
  if (e < E) {
    int s = src[e];
    float ds = dinv[s];
    int p = atomicAdd(&cursor[dst[e]], 1);
    sp[p] = make_int2(s, __float_as_int(ds));
  }
}

// ---- fusedA: gather Ax (16 nodes/block, quarter-wave, unroll-8) + MFMA W1,relu,b1 + MFMA W2 ----
// Layouts (m89/m91): A[m=lane&15][k=(lane>>4)*8+j]; C/D col=lane&15, row=(lane>>4)*4+reg.

__global__ __launch_bounds__(256) void fusedA_k(const void* __restrict__ xraw,
                                                const int2* __restrict__ sp,
                                                const int4* __restrict__ ninfo,
                                                const u16* __restrict__ W1t,
                                                const u16* __restrict__ b1,
                                                const u16* __restrict__ W2t,
                                                u16* __restrict__ g, int n,
                                                const int* __restrict__ mode) {
  __shared__ __align__(16) u16 As[16 * 136];
  __shared__ __align__(16) u16 Hs[16 * 136];
  const int tid = threadIdx.x, wv = tid >> 6, lane = tid & 63;
  const int lq = lane >> 4, lr = lane & 15;
  const int mcv = *mode;
  const int base = blockIdx.x * 16;
  const int i = base + wv * 4 + lq;
  const bool valid = (i < n);

  int start = 0, c = 0;
  float di = 0.f;
  if (valid) {
    int4 ni = ninfo[i];
    start = ni.x;
    c = ni.y;
    di = __int_as_float(ni.z);
  }
  float acc[8];
  {
    float f[8] = {0.f, 0.f, 0.f, 0.f, 0.f, 0.f, 0.f, 0.f};
    if (valid) load8x(xraw, i, lr, mcv, f);
#pragma unroll
    for (int j = 0; j < 8; ++j) acc[j] = f[j] * di;
  }
  const int bl = lq * 16;
  for (int bs = 0; __any(bs < c); bs += 16) {
    int m = c - bs;
    m = m < 0 ? 0 : (m > 16 ? 16 : m);
    int s = 0, db = 0;
    if (lr < m) {
      int2 p = sp[start + bs + lr];
      s = p.x;
      db = p.y;
    }
    int mmw = m;
    mmw = max(mmw, __shfl_xor(mmw, 16));
    mmw = max(mmw, __shfl_xor(mmw, 32));
    // unroll-8 clusters; zero-padded lanes (s=0,d=0) make over-issue harmless
    for (int e = 0; e < mmw; e += 8) {
      int sx[8];
      float dx[8];
#pragma unroll
      for (int k = 0; k < 8; ++k) {
        sx[k] = __shfl(s, bl + e + k);
        dx[k] = __int_as_float(__shfl(db, bl + e + k));
      }
      float fx[8][8];
#pragma unroll
      for (int k = 0; k < 8; ++k) load8x(xraw, sx[k], lr, mcv, fx[k]);
#pragma unroll
      for (int k = 0; k < 8; ++k)
#pragma unroll
        for (int j = 0; j < 8; ++j) acc[j] = fmaf(fx[k][j], dx[k], acc[j]);
    }
  }
  {
    uint4 ov;
    ov.x = pk2(acc[0] * di, acc[1] * di);
    ov.y = pk2(acc[2] * di, acc[3] * di);
    ov.z = pk2(acc[4] * di, acc[5] * di);
    ov.w = pk2(acc[6] * di, acc[7] * di);
    *(uint4*)&As[(wv * 4 + lq) * 136 + lr * 8] = ov;
  }
  __syncthreads();

  // W1: wave wv -> col tiles 2wv, 2wv+1
  bf16x8 a[4];
#pragma unroll
  for (int s = 0; s < 4; ++s)
    a[s] = *(const bf16x8*)&As[lr * 136 + s * 32 + lq * 8];
#pragma unroll
  for (int t = 0; t < 2; ++t) {
    const int nt = wv * 2 + t;
    f32x4 acc4 = {0.f, 0.f, 0.f, 0.f};
#pragma unroll
    for (int s = 0; s < 4; ++s) {
      bf16x8 b = *(const bf16x8*)&W1t[(nt * 16 + lr) * 128 + s * 32 + lq * 8];
      acc4 = __builtin_amdgcn_mfma_f32_16x16x32_bf16(a[s], b, acc4, 0, 0, 0);
    }
    float bb = b2f(b1[nt * 16 + lr]);
#pragma unroll
    for (int r = 0; r < 4; ++r) {
      float o = fmaxf(acc4[r] + bb, 0.f);
      Hs[(lq * 4 + r) * 136 + nt * 16 + lr] = f2b(o);
    }
  }
  __syncthreads();

  // W2: wave wv -> col tile wv
  bf16x8 a2[4];
#pragma unroll
  for (int s = 0; s < 4; ++s)
    a2[s] = *(const bf16x8*)&Hs[lr * 136 + s * 32 + lq * 8];
  {
    const int nt = wv;
    f32x4 acc4 = {0.f, 0.f, 0.f, 0.f};
#pragma unroll
    for (int s = 0; s < 4; ++s) {
      bf16x8 b = *(const bf16x8*)&W2t[(nt * 16 + lr) * 128 + s * 32 + lq * 8];
      acc4 = __builtin_amdgcn_mfma_f32_16x16x32_bf16(a2[s], b, acc4, 0, 0, 0);
    }
#pragma unroll
    for (int r = 0; r < 4; ++r) {
      int row = base + lq * 4 + r;
      if (row < n) g[(size_t)row * 64 + nt * 16 + lr] = f2b(acc4[r]);
    }
  }
}

// ---- agg2: oct-wave over g, 8 nodes/wave, unroll-8 ----

__global__ __launch_bounds__(256) void agg2_k(const u16* __restrict__ g,
                                              const int2* __restrict__ sp,
                                              const int4* __restrict__ ninfo,
                                              const u16* __restrict__ b2,
                                              void* __restrict__ outv, int n,
                                              const int* __restrict__ mode) {
  const int lane = threadIdx.x & 63;
  const int o8 = lane >> 3, l8 = lane & 7;
  const int i = blockIdx.x * 32 + (threadIdx.x >> 6) * 8 + o8;
  const bool valid = (i < n);

  int start = 0, c = 0;
  float di = 0.f;
  if (valid) {
    int4 ni = ninfo[i];
    start = ni.x;
    c = ni.y;
    di = __int_as_float(ni.z);
  }
  float acc[8];
  {
    uint4 v = valid ? *(const uint4*)(g + (size_t)i * 64 + l8 * 8)
                    : make_uint4(0u, 0u, 0u, 0u);
    float f[8];
    dec8(v, f);
#pragma unroll
    for (int j = 0; j < 8; ++j) acc[j] = f[j] * di;
  }
  const int bl = o8 * 8;
  for (int base = 0; __any(base < c); base += 8) {
    int m = c - base;
    m = m < 0 ? 0 : (m > 8 ? 8 : m);
    int s = 0, db = 0;
    if (l8 < m) {
      int2 p = sp[start + base + l8];
      s = p.x;
      db = p.y;
    }
    // one unroll-8 cluster covers the whole batch (zero-padded lanes harmless)
    int sx[8];
    float dx[8];
#pragma unroll
    for (int k = 0; k < 8; ++k) {
      sx[k] = __shfl(s, bl + k);
      dx[k] = __int_as_float(__shfl(db, bl + k));
    }
    uint4 vx[8];
#pragma unroll
    for (int k = 0; k < 8; ++k)
      vx[k] = *(const uint4*)(g + (size_t)sx[k] * 64 + l8 * 8);
#pragma unroll
    for (int k = 0; k < 8; ++k) fma8(vx[k], dx[k], acc);
  }
  if (valid) {
    uint4 bv = *(const uint4*)(b2 + l8 * 8);
    float bf[8];
    dec8(bv, bf);
    float o[8];
#pragma unroll
    for (int j = 0; j < 8; ++j) o[j] = fmaf(acc[j], di, bf[j]);
    if (*mode) {
      float* op = (float*)outv + (size_t)i * 64 + l8 * 8;
      *(float4*)op = make_float4(o[0], o[1], o[2], o[3]);
      *(float4*)(op + 4) = make_float4(o[4], o[5], o[6], o[7]);
    } else {
      uint4 ov;
      ov.x = pk2(o[0], o[1]);
      ov.y = pk2(o[2], o[3]);
      ov.z = pk2(o[4], o[5]);
      ov.w = pk2(o[6], o[7]);
      *(uint4*)((u16*)outv + (size_t)i * 64 + l8 * 8) = ov;
    }
  }
}

// ================= launch =================

extern "C" void kernel_launch(void* const* d_in, const int* in_sizes, int n_in,
                              void* d_out, int out_size, void* d_ws, size_t ws_size,
                              hipStream_t stream) {
  const void* x_raw  = d_in[0];
  const int*  ei     = (const int*)d_in[1];
  const void* W1_raw = d_in[2];
  const void* b1_raw = d_in[3];
  const void* W2_raw = d_in[4];
  const void* b2_raw = d_in[5];

  const int N = in_sizes[0] / 128;
  const int E = in_sizes[1] / 2;
  const int NP = ((N + 255) / 256) * 256;
  const int NB = NP / 256;

  char* ws = (char*)d_ws;
  size_t off = 0;
  auto alloc = [&](size_t bytes) -> void* {
    void* p = ws + off;
    off = (off + bytes + 255) & ~(size_t)255;
    return p;
  };
  int*   mode   = (int*)alloc(4);
  int*   cnt    = (int*)alloc((size_t)NP * 4);
  float* dinv   = (float*)alloc((size_t)NP * 4);
  int*   offs   = (int*)alloc((size_t)NP * 4);
  int*   cursor = (int*)alloc((size_t)NP * 4);
  int*   bsum   = (int*)alloc(1024 * 4);
  int4*  ninfo  = (int4*)alloc((size_t)NP * 16);
  int2*  sp     = (int2*)alloc((size_t)E * 8);
  u16*   W1t    = (u16*)alloc((size_t)128 * 128 * 2);
  u16*   b1b    = (u16*)alloc(128 * 2);
  u16*   W2t    = (u16*)alloc((size_t)64 * 128 * 2);
  u16*   b2b    = (u16*)alloc(64 * 2);
  u16*   g      = (u16*)alloc((size_t)N * 64 * 2);

  const int eb = (E + 255) / 256;
  prep_k<<<NB, 256, 0, stream>>>(W1_raw, b1_raw, W2_raw, b2_raw,
                                 W1t, b1b, W2t, b2b, mode, cnt, NP);
  count_k<<<eb, 256, 0, stream>>>(ei + E, cnt, E);
  scan1<<<NB, 256, 0, stream>>>(cnt, offs, bsum, NP);
  scan23<<<NB, 256, 0, stream>>>(offs, bsum, cursor, cnt, dinv, ninfo, NP);
  fill_k<<<eb, 256, 0, stream>>>(ei, ei + E, cursor, dinv, sp, E);
  fusedA_k<<<(N + 15) / 16, 256, 0, stream>>>(x_raw, sp, ninfo, W1t, b1b, W2t, g, N, mode);
  agg2_k<<<(N + 31) / 32, 256, 0, stream>>>(g, sp, ninfo, b2b, d_out, N, mode);
}

// Round 9
// 239.940 us; speedup vs baseline: 3.9709x; 1.0383x over previous
//
#include <hip/hip_runtime.h>

// StandGCN2: 2-layer GCN, N=100000, E=600000, 128->128(relu)->64, bf16 I/O.
// R9: gather WARM data. R4 evidence: gathering freshly-written h = 86 MB FETCH
// vs cold x = 166 MB (L2 keeps fresh writes; cold rows re-fetch per XCD).
// Pipeline (8 dispatches): prep(zero+probe+cvtw) -> count -> scan1 -> scan23
// -> fill -> gemm1(x@W1 -> h, dense MFMA) -> fusedB(gather h, agg, +b1, relu,
// MFMA W2 -> g) -> agg2(gather g, +b2 -> out). Gathers: unroll-4 (R6-proven).

typedef unsigned short u16;
typedef unsigned int u32;
typedef __attribute__((ext_vector_type(8))) short bf16x8;
typedef __attribute__((ext_vector_type(4))) float f32x4;

__device__ __forceinline__ float b2f(u16 s) {
  return __uint_as_float(((u32)s) << 16);
}
__device__ __forceinline__ u16 f2b(float f) {
  u32 u = __float_as_uint(f);
  u32 r = (u + 0x7FFFu + ((u >> 16) & 1u)) >> 16;
  return (u16)r;
}
__device__ __forceinline__ u32 pk2(float a, float b) {
  return (u32)f2b(a) | ((u32)f2b(b) << 16);
}
__device__ __forceinline__ void dec8(uint4 v, float f[8]) {
  f[0] = __uint_as_float(v.x << 16);
  f[1] = __uint_as_float(v.x & 0xFFFF0000u);
  f[2] = __uint_as_float(v.y << 16);
  f[3] = __uint_as_float(v.y & 0xFFFF0000u);
  f[4] = __uint_as_float(v.z << 16);
  f[5] = __uint_as_float(v.z & 0xFFFF0000u);
  f[6] = __uint_as_float(v.w << 16);
  f[7] = __uint_as_float(v.w & 0xFFFF0000u);
}
__device__ __forceinline__ void fma8(uint4 v, float d, float acc[8]) {
  acc[0] = fmaf(__uint_as_float(v.x << 16), d, acc[0]);
  acc[1] = fmaf(__uint_as_float(v.x & 0xFFFF0000u), d, acc[1]);
  acc[2] = fmaf(__uint_as_float(v.y << 16), d, acc[2]);
  acc[3] = fmaf(__uint_as_float(v.y & 0xFFFF0000u), d, acc[3]);
  acc[4] = fmaf(__uint_as_float(v.z << 16), d, acc[4]);
  acc[5] = fmaf(__uint_as_float(v.z & 0xFFFF0000u), d, acc[5]);
  acc[6] = fmaf(__uint_as_float(v.w << 16), d, acc[6]);
  acc[7] = fmaf(__uint_as_float(v.w & 0xFFFF0000u), d, acc[7]);
}

// ---- prep: zero cnt + block-local dtype probe + weight convert ----
// W1b: plain bf16 copy (gemm1 transposes into LDS itself); W2t: transposed.

__global__ __launch_bounds__(256) void prep_k(const void* __restrict__ W1,
                                              const void* __restrict__ b1,
                                              const void* __restrict__ W2,
                                              const void* __restrict__ b2,
                                              u16* __restrict__ W1b, u16* __restrict__ ob1,
                                              u16* __restrict__ W2t, u16* __restrict__ ob2,
                                              int* __restrict__ mode,
                                              int* __restrict__ cnt, int np) {
  __shared__ int cnt_s;
  const int tid = threadIdx.x;
  int i = blockIdx.x * 256 + tid;
  if (i < np) cnt[i] = 0;

  if (tid == 0) cnt_s = 0;
  __syncthreads();
  int c = 0;
  for (int j = tid; j < 4096; j += 256) {
    u32 e = (((const u16*)W1)[j] >> 7) & 0xFFu;
    if (e >= 100u && e <= 130u) c++;
  }
  atomicAdd(&cnt_s, c);
  __syncthreads();
  const int m = (cnt_s < 3328) ? 1 : 0;  // 1 = fp32
  if (blockIdx.x == 0 && tid == 0) *mode = m;

  if (i < 24768) {
    int j = i;
    const void* src;
    u16* dst;
    int sidx, didx;
    if (j < 16384) {
      src = W1; dst = W1b; sidx = j; didx = j;  // plain copy
    } else if ((j -= 16384) < 128) {
      src = b1; dst = ob1; sidx = j; didx = j;
    } else if ((j -= 128) < 8192) {
      int nn = j >> 7, k = j & 127;               // W2t[n][k] = W2[k][n]
      src = W2; dst = W2t; sidx = k * 64 + nn; didx = j;
    } else {
      j -= 8192;
      src = b2; dst = ob2; sidx = j; didx = j;
    }
    dst[didx] = m ? f2b(((const float*)src)[sidx]) : ((const u16*)src)[sidx];
  }
}

// ---------------- CSR build ----------------

__global__ __launch_bounds__(256) void count_k(const int* __restrict__ dst,
                                               int* __restrict__ cnt, int E) {
  int e = blockIdx.x * 256 + threadIdx.x;
  if (e < E) atomicAdd(&cnt[dst[e]], 1);
}

__global__ __launch_bounds__(256) void scan1(const int* __restrict__ cnt,
                                             int* __restrict__ offs,
                                             int* __restrict__ bsum, int np) {
  __shared__ int lds[256];
  int t = threadIdx.x;
  int i = blockIdx.x * 256 + t;
  int v = cnt[i];
  lds[t] = v;
  __syncthreads();
#pragma unroll
  for (int off = 1; off < 256; off <<= 1) {
    int add = (t >= off) ? lds[t - off] : 0;
    __syncthreads();
    lds[t] += add;
    __syncthreads();
  }
  offs[i] = lds[t] - v;
  if (t == 0) bsum[blockIdx.x] = lds[255];
}

__global__ __launch_bounds__(256) void scan23(const int* __restrict__ offs,
                                              const int* __restrict__ bsum,
                                              int* __restrict__ cursor,
                                              const int* __restrict__ cnt,
                                              float* __restrict__ dinv,
                                              int4* __restrict__ ninfo, int np) {
  __shared__ int lds[256];
  const int t = threadIdx.x, b = blockIdx.x;
  int part = 0;
  for (int k = t; k < b; k += 256) part += bsum[k];
  lds[t] = part;
  __syncthreads();
#pragma unroll
  for (int off = 128; off > 0; off >>= 1) {
    if (t < off) lds[t] += lds[t + off];
    __syncthreads();
  }
  const int pre = lds[0];
  int i = b * 256 + t;
  int o = offs[i] + pre;
  cursor[i] = o;
  int c = cnt[i];
  float dv = rsqrtf((float)c + 1.0f);  // +1 self-loop
  dinv[i] = dv;
  ninfo[i] = make_int4(o, c, __float_as_int(dv), 0);
}

__global__ __launch_bounds__(256) void fill_k(const int* __restrict__ src,
                                              const int* __restrict__ dst,
                                              int* __restrict__ cursor,
                                              const float* __restrict__ dinv,
                                              int2* __restrict__ sp, int E) {
  int e = blockIdx.x * 256 + threadIdx.x;
  if (e < E) {
    int s = src[e];
    float ds = dinv[s];
    int p = atomicAdd(&cursor[dst[e]], 1);
    sp[p] = make_int2(s, __float_as_int(ds));
  }
}

// ---------------- gemm1: h = x @ W1 (dense MFMA, R2-proven) ----------------
// Layouts (m89/m91): A[m=lane&15][k=(lane>>4)*8+j]; C/D col=lane&15, row=(lane>>4)*4+reg.

__global__ __launch_bounds__(256) void gemm1_k(const void* __restrict__ Araw,
                                               const u16* __restrict__ W,
                                               u16* __restrict__ out, int M,
                                               const int* __restrict__ mode) {
  __shared__ __align__(16) u16 Wt[128 * 136];
  __shared__ __align__(16) u16 As[64 * 136];
  const int tid = threadIdx.x;
  const int mcv = *mode;

  for (int idx = tid; idx < 128 * 128; idx += 256) {
    int n = idx & 127;
    int k = idx >> 7;
    Wt[n * 136 + k] = W[k * 128 + n];
  }
  __syncthreads();

  const int wv = tid >> 6, lane = tid & 63, lr = lane & 15, lq = lane >> 4;
  const int ntiles = (M + 63) >> 6;

  for (int t = blockIdx.x; t < ntiles; t += gridDim.x) {
    const int r0 = t * 64;
    __syncthreads();
    for (int idx = tid; idx < 64 * 16; idx += 256) {
      int row = idx >> 4, c = idx & 15;
      uint4 v = make_uint4(0u, 0u, 0u, 0u);
      if (r0 + row < M) {
        if (mcv) {
          const float* xf = (const float*)Araw + (size_t)(r0 + row) * 128 + c * 8;
          float4 f0 = *(const float4*)xf;
          float4 f1 = *(const float4*)(xf + 4);
          v.x = pk2(f0.x, f0.y);
          v.y = pk2(f0.z, f0.w);
          v.z = pk2(f1.x, f1.y);
          v.w = pk2(f1.z, f1.w);
        } else {
          v = *(const uint4*)((const u16*)Araw + (size_t)(r0 + row) * 128 + c * 8);
        }
      }
      *(uint4*)&As[row * 136 + c * 8] = v;
    }
    __syncthreads();

    bf16x8 a[4];
#pragma unroll
    for (int s = 0; s < 4; ++s)
      a[s] = *(const bf16x8*)&As[(wv * 16 + lr) * 136 + s * 32 + lq * 8];

#pragma unroll
    for (int nt = 0; nt < 8; ++nt) {
      f32x4 acc = {0.f, 0.f, 0.f, 0.f};
#pragma unroll
      for (int s = 0; s < 4; ++s) {
        bf16x8 b = *(const bf16x8*)&Wt[(nt * 16 + lr) * 136 + s * 32 + lq * 8];
        acc = __builtin_amdgcn_mfma_f32_16x16x32_bf16(a[s], b, acc, 0, 0, 0);
      }
#pragma unroll
      for (int r = 0; r < 4; ++r) {
        int row = r0 + wv * 16 + lq * 4 + r;
        if (row < M) out[(size_t)row * 128 + nt * 16 + lr] = f2b(acc[r]);
      }
    }
  }
}

// ---- fusedB: gather-aggregate h (16 nodes/block, quarter-wave, unroll-4)
//      -> +b1, relu -> LDS tile -> MFMA W2t -> g[N,64] ----

__global__ __launch_bounds__(256) void fusedB_k(const u16* __restrict__ h,
                                                const int2* __restrict__ sp,
                                                const int4* __restrict__ ninfo,
                                                const u16* __restrict__ b1,
                                                const u16* __restrict__ W2t,
                                                u16* __restrict__ g, int n) {
  __shared__ __align__(16) u16 As[16 * 136];
  const int tid = threadIdx.x, wv = tid >> 6, lane = tid & 63;
  const int lq = lane >> 4, lr = lane & 15;
  const int base = blockIdx.x * 16;
  const int i = base + wv * 4 + lq;
  const bool valid = (i < n);

  int start = 0, c = 0;
  float di = 0.f;
  if (valid) {
    int4 ni = ninfo[i];
    start = ni.x;
    c = ni.y;
    di = __int_as_float(ni.z);
  }
  float acc[8];
  {
    uint4 v = valid ? *(const uint4*)(h + (size_t)i * 128 + lr * 8)
                    : make_uint4(0u, 0u, 0u, 0u);
    float f[8];
    dec8(v, f);
#pragma unroll
    for (int j = 0; j < 8; ++j) acc[j] = f[j] * di;
  }
  const int bl = lq * 16;
  for (int bs = 0; __any(bs < c); bs += 16) {
    int m = c - bs;
    m = m < 0 ? 0 : (m > 16 ? 16 : m);
    int s = 0, db = 0;
    if (lr < m) {
      int2 p = sp[start + bs + lr];
      s = p.x;
      db = p.y;
    }
    int mmw = m;
    mmw = max(mmw, __shfl_xor(mmw, 16));
    mmw = max(mmw, __shfl_xor(mmw, 32));
    for (int e = 0; e < mmw; e += 4) {
      int s0 = __shfl(s, bl + e), s1 = __shfl(s, bl + e + 1);
      int s2 = __shfl(s, bl + e + 2), s3 = __shfl(s, bl + e + 3);
      float d0 = __int_as_float(__shfl(db, bl + e));
      float d1 = __int_as_float(__shfl(db, bl + e + 1));
      float d2 = __int_as_float(__shfl(db, bl + e + 2));
      float d3 = __int_as_float(__shfl(db, bl + e + 3));
      uint4 v0 = *(const uint4*)(h + (size_t)s0 * 128 + lr * 8);
      uint4 v1 = *(const uint4*)(h + (size_t)s1 * 128 + lr * 8);
      uint4 v2 = *(const uint4*)(h + (size_t)s2 * 128 + lr * 8);
      uint4 v3 = *(const uint4*)(h + (size_t)s3 * 128 + lr * 8);
      fma8(v0, d0, acc);
      fma8(v1, d1, acc);
      fma8(v2, d2, acc);
      fma8(v3, d3, acc);
    }
  }
  // h1 = relu(acc*di + b1) -> As tile (bf16)
  {
    uint4 bv = *(const uint4*)(b1 + lr * 8);
    float bf[8];
    dec8(bv, bf);
    float o[8];
#pragma unroll
    for (int j = 0; j < 8; ++j) o[j] = fmaxf(fmaf(acc[j], di, bf[j]), 0.f);
    uint4 ov;
    ov.x = pk2(o[0], o[1]);
    ov.y = pk2(o[2], o[3]);
    ov.z = pk2(o[4], o[5]);
    ov.w = pk2(o[6], o[7]);
    *(uint4*)&As[(wv * 4 + lq) * 136 + lr * 8] = ov;
  }
  __syncthreads();

  // W2 MFMA: wave wv -> col tile wv (cols 16wv..16wv+15)
  bf16x8 a[4];
#pragma unroll
  for (int s = 0; s < 4; ++s)
    a[s] = *(const bf16x8*)&As[lr * 136 + s * 32 + lq * 8];
  {
    const int nt = wv;
    f32x4 acc4 = {0.f, 0.f, 0.f, 0.f};
#pragma unroll
    for (int s = 0; s < 4; ++s) {
      bf16x8 b = *(const bf16x8*)&W2t[(nt * 16 + lr) * 128 + s * 32 + lq * 8];
      acc4 = __builtin_amdgcn_mfma_f32_16x16x32_bf16(a[s], b, acc4, 0, 0, 0);
    }
#pragma unroll
    for (int r = 0; r < 4; ++r) {
      int row = base + lq * 4 + r;
      if (row < n) g[(size_t)row * 64 + nt * 16 + lr] = f2b(acc4[r]);
    }
  }
}

// ---- agg2: oct-wave over g, 8 nodes/wave, unroll-4 ----

__global__ __launch_bounds__(256) void agg2_k(const u16* __restrict__ g,
                                              const int2* __restrict__ sp,
                                              const int4* __restrict__ ninfo,
                                              const u16* __restrict__ b2,
                                              void* __restrict__ outv, int n,
                                              const int* __restrict__ mode) {
  const int lane = threadIdx.x & 63;
  const int o8 = lane >> 3, l8 = lane & 7;
  const int i = blockIdx.x * 32 + (threadIdx.x >> 6) * 8 + o8;
  const bool valid = (i < n);

  int start = 0, c = 0;
  float di = 0.f;
  if (valid) {
    int4 ni = ninfo[i];
    start = ni.x;
    c = ni.y;
    di = __int_as_float(ni.z);
  }
  float acc[8];
  {
    uint4 v = valid ? *(const uint4*)(g + (size_t)i * 64 + l8 * 8)
                    : make_uint4(0u, 0u, 0u, 0u);
    float f[8];
    dec8(v, f);
#pragma unroll
    for (int j = 0; j < 8; ++j) acc[j] = f[j] * di;
  }
  const int bl = o8 * 8;
  for (int base = 0; __any(base < c); base += 8) {
    int m = c - base;
    m = m < 0 ? 0 : (m > 8 ? 8 : m);
    int s = 0, db = 0;
    if (l8 < m) {
      int2 p = sp[start + base + l8];
      s = p.x;
      db = p.y;
    }
    int mmw = m;
    mmw = max(mmw, __shfl_xor(mmw, 8));
    mmw = max(mmw, __shfl_xor(mmw, 16));
    mmw = max(mmw, __shfl_xor(mmw, 32));
    for (int e = 0; e < mmw; e += 4) {
      int s0 = __shfl(s, bl + e), s1 = __shfl(s, bl + e + 1);
      int s2 = __shfl(s, bl + e + 2), s3 = __shfl(s, bl + e + 3);
      float d0 = __int_as_float(__shfl(db, bl + e));
      float d1 = __int_as_float(__shfl(db, bl + e + 1));
      float d2 = __int_as_float(__shfl(db, bl + e + 2));
      float d3 = __int_as_float(__shfl(db, bl + e + 3));
      uint4 v0 = *(const uint4*)(g + (size_t)s0 * 64 + l8 * 8);
      uint4 v1 = *(const uint4*)(g + (size_t)s1 * 64 + l8 * 8);
      uint4 v2 = *(const uint4*)(g + (size_t)s2 * 64 + l8 * 8);
      uint4 v3 = *(const uint4*)(g + (size_t)s3 * 64 + l8 * 8);
      fma8(v0, d0, acc);
      fma8(v1, d1, acc);
      fma8(v2, d2, acc);
      fma8(v3, d3, acc);
    }
  }
  if (valid) {
    uint4 bv = *(const uint4*)(b2 + l8 * 8);
    float bf[8];
    dec8(bv, bf);
    float o[8];
#pragma unroll
    for (int j = 0; j < 8; ++j) o[j] = fmaf(acc[j], di, bf[j]);
    if (*mode) {
      float* op = (float*)outv + (size_t)i * 64 + l8 * 8;
      *(float4*)op = make_float4(o[0], o[1], o[2], o[3]);
      *(float4*)(op + 4) = make_float4(o[4], o[5], o[6], o[7]);
    } else {
      uint4 ov;
      ov.x = pk2(o[0], o[1]);
      ov.y = pk2(o[2], o[3]);
      ov.z = pk2(o[4], o[5]);
      ov.w = pk2(o[6], o[7]);
      *(uint4*)((u16*)outv + (size_t)i * 64 + l8 * 8) = ov;
    }
  }
}

// ================= launch =================

extern "C" void kernel_launch(void* const* d_in, const int* in_sizes, int n_in,
                              void* d_out, int out_size, void* d_ws, size_t ws_size,
                              hipStream_t stream) {
  const void* x_raw  = d_in[0];
  const int*  ei     = (const int*)d_in[1];
  const void* W1_raw = d_in[2];
  const void* b1_raw = d_in[3];
  const void* W2_raw = d_in[4];
  const void* b2_raw = d_in[5];

  const int N = in_sizes[0] / 128;
  const int E = in_sizes[1] / 2;
  const int NP = ((N + 255) / 256) * 256;
  const int NB = NP / 256;

  char* ws = (char*)d_ws;
  size_t off = 0;
  auto alloc = [&](size_t bytes) -> void* {
    void* p = ws + off;
    off = (off + bytes + 255) & ~(size_t)255;
    return p;
  };
  int*   mode   = (int*)alloc(4);
  int*   cnt    = (int*)alloc((size_t)NP * 4);
  float* dinv   = (float*)alloc((size_t)NP * 4);
  int*   offs   = (int*)alloc((size_t)NP * 4);
  int*   cursor = (int*)alloc((size_t)NP * 4);
  int*   bsum   = (int*)alloc(1024 * 4);
  int4*  ninfo  = (int4*)alloc((size_t)NP * 16);
  int2*  sp     = (int2*)alloc((size_t)E * 8);
  u16*   W1b    = (u16*)alloc((size_t)128 * 128 * 2);
  u16*   b1b    = (u16*)alloc(128 * 2);
  u16*   W2t    = (u16*)alloc((size_t)64 * 128 * 2);
  u16*   b2b    = (u16*)alloc(64 * 2);
  u16*   h      = (u16*)alloc((size_t)N * 128 * 2);
  u16*   g      = (u16*)alloc((size_t)N * 64 * 2);

  const int eb = (E + 255) / 256;
  prep_k<<<NB, 256, 0, stream>>>(W1_raw, b1_raw, W2_raw, b2_raw,
                                 W1b, b1b, W2t, b2b, mode, cnt, NP);
  count_k<<<eb, 256, 0, stream>>>(ei + E, cnt, E);
  scan1<<<NB, 256, 0, stream>>>(cnt, offs, bsum, NP);
  scan23<<<NB, 256, 0, stream>>>(offs, bsum, cursor, cnt, dinv, ninfo, NP);
  fill_k<<<eb, 256, 0, stream>>>(ei, ei + E, cursor, dinv, sp, E);
  gemm1_k<<<512, 256, 0, stream>>>(x_raw, W1b, h, N, mode);
  fusedB_k<<<(N + 15) / 16, 256, 0, stream>>>(h, sp, ninfo, b1b, W2t, g, N);
  agg2_k<<<(N + 31) / 32, 256, 0, stream>>>(g, sp, ninfo, b2b, d_out, N, mode);
}